// Round 9
// baseline (1882.572 us; speedup 1.0000x reference)
//
#include <hip/hip_runtime.h>
#include <hip/hip_fp16.h>

#define NN 100000
#define NE 3200000
#define SG 2048
#define OUTC 384
#define EPS 1e-5f

#define NBUK 800
#define BNODES 125
#define CAP 5120
#define TILE 4096
#define B_BUCKET 782      // ceil(NE/TILE)
#define B_GEMM 391        // ceil(NN/256)
#define LDSTRIDE 136

// panel-partitioned aggregation
#define NPAN 8
#define CPP 256           // chunks per panel
#define CHUNKP 98         // nodes per wave (98*4*256 = 100352 >= NN)
#define CHKB (4 * CHUNKP) // nodes per block-chunk
#define AGGP_GRID 4096    // oversubscribed; extra blocks exit

typedef _Float16 f16x8 __attribute__((ext_vector_type(8)));
typedef float f32x16 __attribute__((ext_vector_type(16)));

// ---------------- init: W transpose prep + zero out/gcur/sums/ctrs ----------------
__global__ void k_init(const float* __restrict__ W1, const float* __restrict__ W2,
                       const float* __restrict__ W3, __half* __restrict__ WT,
                       unsigned int* __restrict__ outz, int* __restrict__ gcur,
                       float* __restrict__ sums, int* __restrict__ ctrs) {
    int g = blockIdx.x * 256 + threadIdx.x;
    int nt = gridDim.x * 256;
    for (int i = g; i < SG * OUTC; i += nt) outz[i] = 0u;
    if (g < NBUK) gcur[g] = 0;
    if (g < 512) sums[g] = 0.f;
    if (g < 24) ctrs[g] = 0;
    for (int i = g; i < 3 * 16384; i += nt) {
        int m = i >> 14, idx = i & 16383;
        int k = idx >> 7, n = idx & 127;
        const float* W = m == 0 ? W1 : (m == 1 ? W2 : W3);
        WT[m * 16384 + n * 128 + k] = __float2half(W[idx]);
    }
}

// ---------------- fused stage 1: bucketA || gemm32 (unscaled, panel layout) ----------------
__device__ void bucketA_body(int* smem, int bb,
                             const int* __restrict__ erow, const int* __restrict__ ecol,
                             int* __restrict__ gcur, int* __restrict__ packed) {
    int* sc   = smem;
    int* sr   = smem + 4096;
    int* hist = smem + 8192;
    int* loff = smem + 9216;
    int* gch  = smem + 10240;
    int* cur  = smem + 11264;
    int* psum = smem + 12288;
    int t = threadIdx.x;
    hist[t] = 0; hist[t + 256] = 0; hist[t + 512] = 0; hist[t + 768] = 0;
    __syncthreads();
    int e0 = bb * TILE;
    int lim = NE - e0; if (lim > TILE) lim = TILE;
    for (int i = t; i < lim; i += 256) {
        int c = ecol[e0 + i];
        int r = erow[e0 + i];
        sc[i] = c; sr[i] = r;
        atomicAdd(&hist[c / BNODES], 1);
    }
    __syncthreads();
    int h0 = hist[4 * t], h1 = hist[4 * t + 1], h2 = hist[4 * t + 2], h3 = hist[4 * t + 3];
    int s = h0 + h1 + h2 + h3;
    psum[t] = s; __syncthreads();
    for (int st = 1; st < 256; st <<= 1) {
        int a = (t >= st) ? psum[t - st] : 0;
        __syncthreads();
        psum[t] += a;
        __syncthreads();
    }
    int base = psum[t] - s;
    loff[4 * t] = base;
    loff[4 * t + 1] = base + h0;
    loff[4 * t + 2] = base + h0 + h1;
    loff[4 * t + 3] = base + h0 + h1 + h2;
#pragma unroll
    for (int j = 0; j < 4; ++j) {
        int b = 4 * t + j;
        if (b < NBUK) {
            int c = hist[b];
            gch[b] = c ? atomicAdd(&gcur[b], c) : 0;
            cur[b] = loff[b];
        }
    }
    __syncthreads();
    for (int i = t; i < lim; i += 256) {
        int c = sc[i], r = sr[i];
        int b = c / BNODES;
        int lc = c - b * BNODES;
        int p = atomicAdd(&cur[b], 1);
        int rank = p - loff[b];
        if (gch[b] + rank < CAP) packed[b * CAP + gch[b] + rank] = r | (lc << 17);
    }
}

// store helper: panel layout, halves address = ((col>>4)*NN + row)*16 + (col&15)
__device__ __forceinline__ void panel_store(__half* __restrict__ C, int row, int col, float v) {
    C[((size_t)(col >> 4) * NN + row) * 16 + (col & 15)] = __float2half(v);
}

__device__ void gemm32u_body(int* smem, int gb, const float* __restrict__ A,
                             const __half* __restrict__ WTg, __half* __restrict__ C) {
    _Float16* Wl = (_Float16*)smem;
    int tid = threadIdx.x;
    for (int ch = tid; ch < 2048; ch += 256) {
        int n = ch >> 4, seg = ch & 15;
        *(uint4*)&Wl[n * LDSTRIDE + seg * 8] = *(const uint4*)(WTg + n * 128 + seg * 8);
    }
    __syncthreads();
    int wave = tid >> 6, lane = tid & 63;
    int l31 = lane & 31, lhi = lane >> 5;
    int rowbase = gb * 256 + wave * 64;
    f32x16 acc[2][4];
#pragma unroll
    for (int rt = 0; rt < 2; ++rt)
#pragma unroll
        for (int nt = 0; nt < 4; ++nt)
#pragma unroll
            for (int i = 0; i < 16; ++i) acc[rt][nt][i] = 0.f;
    int r0 = rowbase + l31;      if (r0 >= NN) r0 = NN - 1;
    int r1 = rowbase + 32 + l31; if (r1 >= NN) r1 = NN - 1;
    const float* A0 = A + (size_t)r0 * 128;
    const float* A1 = A + (size_t)r1 * 128;
#pragma unroll
    for (int ks = 0; ks < 8; ++ks) {
        int koff = ks * 16 + lhi * 8;
        float4 f0 = *(const float4*)(A0 + koff);
        float4 f1 = *(const float4*)(A0 + koff + 4);
        float4 g0 = *(const float4*)(A1 + koff);
        float4 g1 = *(const float4*)(A1 + koff + 4);
        f16x8 a0, a1;
        a0[0] = (_Float16)f0.x; a0[1] = (_Float16)f0.y; a0[2] = (_Float16)f0.z; a0[3] = (_Float16)f0.w;
        a0[4] = (_Float16)f1.x; a0[5] = (_Float16)f1.y; a0[6] = (_Float16)f1.z; a0[7] = (_Float16)f1.w;
        a1[0] = (_Float16)g0.x; a1[1] = (_Float16)g0.y; a1[2] = (_Float16)g0.z; a1[3] = (_Float16)g0.w;
        a1[4] = (_Float16)g1.x; a1[5] = (_Float16)g1.y; a1[6] = (_Float16)g1.z; a1[7] = (_Float16)g1.w;
#pragma unroll
        for (int nt = 0; nt < 4; ++nt) {
            f16x8 b = *(const f16x8*)&Wl[(nt * 32 + l31) * LDSTRIDE + ks * 16 + lhi * 8];
            acc[0][nt] = __builtin_amdgcn_mfma_f32_32x32x16_f16(a0, b, acc[0][nt], 0, 0, 0);
            acc[1][nt] = __builtin_amdgcn_mfma_f32_32x32x16_f16(a1, b, acc[1][nt], 0, 0, 0);
        }
    }
#pragma unroll
    for (int rt = 0; rt < 2; ++rt) {
#pragma unroll
        for (int r = 0; r < 16; ++r) {
            int row = rowbase + rt * 32 + (r & 3) + 8 * (r >> 2) + 4 * lhi;
            if (row < NN) {
#pragma unroll
                for (int nt = 0; nt < 4; ++nt)
                    panel_store(C, row, nt * 32 + l31, acc[rt][nt][r]);
            }
        }
    }
}

__global__ __launch_bounds__(256, 2) void k_fused1(const int* __restrict__ erow,
                                                   const int* __restrict__ ecol,
                                                   int* __restrict__ gcur,
                                                   int* __restrict__ packed,
                                                   const float* __restrict__ x,
                                                   const __half* __restrict__ WT,
                                                   __half* __restrict__ XWp) {
    __shared__ __align__(16) int smem[12544];
    int bb = blockIdx.x;
    if (bb < B_BUCKET) bucketA_body(smem, bb, erow, ecol, gcur, packed);
    else gemm32u_body(smem, bb - B_BUCKET, x, WT, XWp);
}

// ---------------- stage B: CSR build + dinv + in-place panel-row scaling ----------------
__global__ __launch_bounds__(256) void k_csrB(int* __restrict__ rows,
                                              const int* __restrict__ gcur,
                                              int* __restrict__ begs, int* __restrict__ ends,
                                              float* __restrict__ dinv,
                                              __half* __restrict__ XWp) {
    __shared__ int lin[CAP];
    __shared__ int hist[128], off[128], cur[128], psc[128];
    __shared__ float dinvl[128];
    int b = blockIdx.x, t = threadIdx.x;
    int cnt = gcur[b]; if (cnt > CAP) cnt = CAP;
    int base = b * CAP;
    for (int i = t; i < cnt; i += 256) lin[i] = rows[base + i];
    if (t < 128) hist[t] = 0;
    __syncthreads();
    for (int i = t; i < cnt; i += 256) atomicAdd(&hist[lin[i] >> 17], 1);
    __syncthreads();
    int pc = 0;
    if (t < 128) { pc = (hist[t] + 3) & ~3; psc[t] = pc; }
    __syncthreads();
    for (int st = 1; st < 128; st <<= 1) {
        int a = 0;
        if (t < 128 && t >= st) a = psc[t - st];
        __syncthreads();
        if (t < 128) psc[t] += a;
        __syncthreads();
    }
    if (t < 128) { off[t] = psc[t] - pc; cur[t] = off[t]; }
    __syncthreads();
    if (t < BNODES) {
        int n = b * BNODES + t;
        int c = hist[t];
        int bg = base + off[t];
        begs[n] = bg;
        ends[n] = bg + c;
        float dv = rsqrtf((float)(c + 1));
        dinv[n] = dv;
        dinvl[t] = dv;
        int pad = (c + 3) & ~3;
        for (int p = c; p < pad; ++p)
            if (off[t] + p < CAP) rows[base + off[t] + p] = 0;
    }
    __syncthreads();
    for (int i = t; i < cnt; i += 256) {
        int w = lin[i];
        int lc = w >> 17;
        int p = atomicAdd(&cur[lc], 1);
        if (p < CAP) rows[base + p] = w & 0x1FFFF;
    }
    // scale this bucket's rows (panel layout) by dinv: 2 threads/row, 1 uint4 per panel each
    int rr = t >> 1, hf = t & 1;
    if (rr < BNODES) {
        float dv = dinvl[rr];
        size_t n = (size_t)b * BNODES + rr;
#pragma unroll
        for (int p = 0; p < NPAN; ++p) {
            uint4* q = (uint4*)(XWp + ((size_t)p * NN + n) * 16) + hf;
            uint4 v = *q;
            __half2* h = (__half2*)&v;
#pragma unroll
            for (int qq = 0; qq < 4; ++qq) {
                float2 f = __half22float2(h[qq]);
                h[qq] = __floats2half2_rn(f.x * dv, f.y * dv);
            }
            *q = v;
        }
    }
}

// ---------------- MFMA GEMM (A fp16 row-major): panel-layout out, scaled by dinv ----------------
__global__ __launch_bounds__(256, 2) void k_gemm16(const __half* __restrict__ A,
                                                   const __half* __restrict__ WTg,
                                                   const float* __restrict__ dinv,
                                                   __half* __restrict__ C) {
    __shared__ _Float16 Wl[128 * LDSTRIDE];
    int tid = threadIdx.x;
    for (int ch = tid; ch < 2048; ch += 256) {
        int n = ch >> 4, seg = ch & 15;
        *(uint4*)&Wl[n * LDSTRIDE + seg * 8] = *(const uint4*)(WTg + n * 128 + seg * 8);
    }
    __syncthreads();
    int wave = tid >> 6, lane = tid & 63;
    int l31 = lane & 31, lhi = lane >> 5;
    int rowbase = blockIdx.x * 256 + wave * 64;
    f32x16 acc[2][4];
#pragma unroll
    for (int rt = 0; rt < 2; ++rt)
#pragma unroll
        for (int nt = 0; nt < 4; ++nt)
#pragma unroll
            for (int i = 0; i < 16; ++i) acc[rt][nt][i] = 0.f;
    int r0 = rowbase + l31;      if (r0 >= NN) r0 = NN - 1;
    int r1 = rowbase + 32 + l31; if (r1 >= NN) r1 = NN - 1;
    const f16x8* A0 = (const f16x8*)(A + (size_t)r0 * 128);
    const f16x8* A1 = (const f16x8*)(A + (size_t)r1 * 128);
#pragma unroll
    for (int ks = 0; ks < 8; ++ks) {
        f16x8 a0 = A0[ks * 2 + lhi];
        f16x8 a1 = A1[ks * 2 + lhi];
#pragma unroll
        for (int nt = 0; nt < 4; ++nt) {
            f16x8 b = *(const f16x8*)&Wl[(nt * 32 + l31) * LDSTRIDE + ks * 16 + lhi * 8];
            acc[0][nt] = __builtin_amdgcn_mfma_f32_32x32x16_f16(a0, b, acc[0][nt], 0, 0, 0);
            acc[1][nt] = __builtin_amdgcn_mfma_f32_32x32x16_f16(a1, b, acc[1][nt], 0, 0, 0);
        }
    }
#pragma unroll
    for (int rt = 0; rt < 2; ++rt) {
#pragma unroll
        for (int r = 0; r < 16; ++r) {
            int row = rowbase + rt * 32 + (r & 3) + 8 * (r >> 2) + 4 * lhi;
            if (row < NN) {
                float sc = dinv[row];
#pragma unroll
                for (int nt = 0; nt < 4; ++nt)
                    panel_store(C, row, nt * 32 + l31, acc[rt][nt][r] * sc);
            }
        }
    }
}

// ---------------- panel-partitioned aggregation core ----------------
// claim a chunk in this block's XCD panel (steal-fallback keeps correctness
// independent of block->XCD mapping); returns chunk id or -1.
__device__ __forceinline__ void claim_chunk(int* ctr, int* s_chunk, int* s_panel) {
    if (threadIdx.x == 0) {
        int xcc = __builtin_amdgcn_s_getreg((3 << 11) | 20) & 7;   // HW_REG_XCC_ID
        int pnl = xcc;
        int c = atomicAdd(&ctr[pnl], 1);
        if (c >= CPP) {
            for (int d = 1; d < 8; ++d) {
                pnl = (xcc + d) & 7;
                c = atomicAdd(&ctr[pnl], 1);
                if (c < CPP) break;
            }
        }
        *s_chunk = (c < CPP) ? c : -1;
        *s_panel = pnl;
    }
}

// per-node gather+sum of one 16-col panel slice; result float2 in lanes 0..7
// lane layout: edge-in-group = lane>>3 (8 edges/gather), col-half2 = lane&7
__device__ __forceinline__ float2 aggp_node(const unsigned int* __restrict__ XW2,
                                            const int* __restrict__ rows,
                                            size_t pbase, int n, int beg, int end,
                                            int lg, int cc) {
    float2 acc = make_float2(0.f, 0.f);
    if (lg == 0) {
        unsigned int sv = XW2[(pbase + n) * 8 + cc];
        float2 f = __half22float2(*(__half2*)&sv);
        acc.x += f.x; acc.y += f.y;
    }
    for (int e = beg; e < end; e += 64) {
        unsigned int vg[8];
#pragma unroll
        for (int g = 0; g < 8; ++g) {
            vg[g] = 0u;
            if (e + g * 8 < end) {                  // wave-uniform
                int idx = e + g * 8 + lg;
                bool val = idx < end;
                int r = val ? rows[idx] : 0;
                unsigned int v = XW2[(pbase + r) * 8 + cc];
                vg[g] = val ? v : 0u;
            }
        }
#pragma unroll
        for (int g = 0; g < 8; ++g) {
            float2 f = __half22float2(*(__half2*)&vg[g]);
            acc.x += f.x; acc.y += f.y;
        }
    }
    acc.x += __shfl_xor(acc.x, 8, 64);  acc.y += __shfl_xor(acc.y, 8, 64);
    acc.x += __shfl_xor(acc.x, 16, 64); acc.y += __shfl_xor(acc.y, 16, 64);
    acc.x += __shfl_xor(acc.x, 32, 64); acc.y += __shfl_xor(acc.y, 32, 64);
    return acc;
}

// conv1/conv2: agg + H write (row-major) + fused column stats
__global__ __launch_bounds__(256, 8) void k_aggp(const __half* __restrict__ XWp,
                                                 const int* __restrict__ begs,
                                                 const int* __restrict__ ends,
                                                 const int* __restrict__ rows,
                                                 const float* __restrict__ dinv,
                                                 __half* __restrict__ H,
                                                 float* __restrict__ sums,
                                                 int* __restrict__ ctr) {
    __shared__ int s_chunk, s_panel;
    __shared__ float sred[4][32];
    claim_chunk(ctr, &s_chunk, &s_panel);
    __syncthreads();
    int chunk = s_chunk;
    if (chunk < 0) return;
    int p = s_panel;
    int wave = threadIdx.x >> 6, lane = threadIdx.x & 63;
    int lg = lane >> 3, cc = lane & 7;
    const unsigned int* XW2 = (const unsigned int*)XWp;
    size_t pbase = (size_t)p * NN;
    int n0 = chunk * CHKB + wave * CHUNKP;
    int n1 = n0 + CHUNKP; if (n1 > NN) n1 = NN;
    float2 ssum = make_float2(0.f, 0.f), sqsum = make_float2(0.f, 0.f);
    for (int n = n0; n < n1; ++n) {
        float2 acc = aggp_node(XW2, rows, pbase, n, begs[n], ends[n], lg, cc);
        if (lg == 0) {
            float dn = dinv[n];
            float vx = acc.x * dn, vy = acc.y * dn;
            __half2 hh = __floats2half2_rn(vx, vy);
            ((unsigned int*)H)[(size_t)n * 64 + p * 8 + cc] = *(unsigned int*)&hh;
            ssum.x += vx; ssum.y += vy;
            sqsum.x += vx * vx; sqsum.y += vy * vy;
        }
    }
    if (lg == 0) {
        sred[wave][cc * 2] = ssum.x;  sred[wave][cc * 2 + 1] = ssum.y;
        sred[wave][16 + cc * 2] = sqsum.x; sred[wave][16 + cc * 2 + 1] = sqsum.y;
    }
    __syncthreads();
    int t = threadIdx.x;
    if (t < 32) {
        float v = sred[0][t] + sred[1][t] + sred[2][t] + sred[3][t];
        int col = p * 16 + (t & 15);
        atomicAdd(&sums[(t < 16 ? 0 : 128) + col], v);
    }
}

// conv3: agg + bias + ReLU + sorted segment-max (no H write)
__global__ __launch_bounds__(256, 8) void k_aggpmax(const __half* __restrict__ XWp,
                                                    const int* __restrict__ begs,
                                                    const int* __restrict__ ends,
                                                    const int* __restrict__ rows,
                                                    const float* __restrict__ dinv,
                                                    const float* __restrict__ b3,
                                                    const int* __restrict__ n2s,
                                                    unsigned int* __restrict__ outmax,
                                                    int* __restrict__ ctr) {
    __shared__ int s_chunk, s_panel;
    claim_chunk(ctr, &s_chunk, &s_panel);
    __syncthreads();
    int chunk = s_chunk;
    if (chunk < 0) return;
    int p = s_panel;
    int wave = threadIdx.x >> 6, lane = threadIdx.x & 63;
    int lg = lane >> 3, cc = lane & 7;
    const unsigned int* XW2 = (const unsigned int*)XWp;
    size_t pbase = (size_t)p * NN;
    int n0 = chunk * CHKB + wave * CHUNKP;
    int n1 = n0 + CHUNKP; if (n1 > NN) n1 = NN;
    float2 bias = make_float2(b3[p * 16 + cc * 2], b3[p * 16 + cc * 2 + 1]);
    int cur = -1;
    float2 runm = make_float2(0.f, 0.f);
    for (int n = n0; n < n1; ++n) {
        float2 acc = aggp_node(XW2, rows, pbase, n, begs[n], ends[n], lg, cc);
        float dn = dinv[n];
        float vx = fmaxf(acc.x * dn + bias.x, 0.f);
        float vy = fmaxf(acc.y * dn + bias.y, 0.f);
        int sg = n2s[n];
        if (sg != cur) {
            if (cur >= 0 && lg == 0) {
                atomicMax(&outmax[cur * OUTC + 256 + p * 16 + cc * 2], __float_as_uint(runm.x));
                atomicMax(&outmax[cur * OUTC + 256 + p * 16 + cc * 2 + 1], __float_as_uint(runm.y));
            }
            cur = sg;
            runm.x = vx; runm.y = vy;
        } else {
            runm.x = fmaxf(runm.x, vx);
            runm.y = fmaxf(runm.y, vy);
        }
    }
    if (cur >= 0 && lg == 0) {
        atomicMax(&outmax[cur * OUTC + 256 + p * 16 + cc * 2], __float_as_uint(runm.x));
        atomicMax(&outmax[cur * OUTC + 256 + p * 16 + cc * 2 + 1], __float_as_uint(runm.y));
    }
}

// ---------------- BN + ReLU (in-place fp16 H) + sorted segment-max ----------------
__global__ void k_bnmax(__half* __restrict__ buf, const float* __restrict__ sums,
                        const float* __restrict__ g, const float* __restrict__ be,
                        const int* __restrict__ n2s,
                        unsigned int* __restrict__ outmax, int colOff) {
    int c = threadIdx.x & 127;
    int rg = threadIdx.x >> 7;
    int n0 = blockIdx.x * 64;
    int nEnd = n0 + 64; if (nEnd > NN) nEnd = NN;
    float mean = sums[c] * (1.0f / NN);
    float inv = rsqrtf(sums[128 + c] * (1.0f / NN) - mean * mean + EPS) * g[c];
    float sc = inv, sh = be[c] - mean * inv;
    int cur = -1; float runmax = 0.f;
    for (int n = n0 + rg; n < nEnd; n += 2) {
        float v = fmaxf(__half2float(buf[(size_t)n * 128 + c]) * sc + sh, 0.f);
        buf[(size_t)n * 128 + c] = __float2half(v);
        int sg = n2s[n];
        if (sg != cur) {
            if (cur >= 0) atomicMax(&outmax[cur * OUTC + colOff + c], __float_as_uint(runmax));
            cur = sg; runmax = v;
        } else {
            runmax = fmaxf(runmax, v);
        }
    }
    if (cur >= 0) atomicMax(&outmax[cur * OUTC + colOff + c], __float_as_uint(runmax));
}

// ---------------- launch ----------------
extern "C" void kernel_launch(void* const* d_in, const int* in_sizes, int n_in,
                              void* d_out, int out_size, void* d_ws, size_t ws_size,
                              hipStream_t stream) {
    const float* x   = (const float*)d_in[0];
    const int*   ei  = (const int*)d_in[1];
    const int*   n2s = (const int*)d_in[2];
    const float* W1  = (const float*)d_in[3];
    const float* g1  = (const float*)d_in[5];
    const float* be1 = (const float*)d_in[6];
    const float* W2  = (const float*)d_in[7];
    const float* g2  = (const float*)d_in[9];
    const float* be2 = (const float*)d_in[10];
    const float* W3  = (const float*)d_in[11];
    const float* b3  = (const float*)d_in[12];

    __half* H    = (__half*)d_ws;                        // NN*128 fp16, row-major
    __half* XWp  = H + (size_t)NN * 128;                 // NN*128 fp16, panel layout
    __half* WT   = XWp + (size_t)NN * 128;               // 3*16384 fp16
    int* rows    = (int*)(WT + 3 * 16384);               // NBUK*CAP
    int* begs    = rows + (size_t)NBUK * CAP;            // NN
    int* ends    = begs + NN;                            // NN
    float* dinv  = (float*)(ends + NN);                  // NN
    int* gcur    = (int*)(dinv + NN);                    // NBUK
    float* sums  = (float*)(gcur + NBUK);                // 512
    int* ctrs    = (int*)(sums + 512);                   // 24

    const int* erow = ei;
    const int* ecol = ei + NE;
    unsigned int* outmax = (unsigned int*)d_out;
    int nbSeg = (NN + 63) / 64;
    int nbG = (NN + 255) / 256;

    k_init<<<512, 256, 0, stream>>>(W1, W2, W3, WT, outmax, gcur, sums, ctrs);
    k_fused1<<<B_BUCKET + B_GEMM, 256, 0, stream>>>(erow, ecol, gcur, rows, x, WT, XWp);
    k_csrB<<<NBUK, 256, 0, stream>>>(rows, gcur, begs, ends, dinv, XWp);

    // conv1
    k_aggp<<<AGGP_GRID, 256, 0, stream>>>(XWp, begs, ends, rows, dinv, H, sums, ctrs);
    k_bnmax<<<nbSeg, 256, 0, stream>>>(H, sums, g1, be1, n2s, outmax, 0);

    // conv2
    k_gemm16<<<nbG, 256, 0, stream>>>(H, WT + 16384, dinv, XWp);
    k_aggp<<<AGGP_GRID, 256, 0, stream>>>(XWp, begs, ends, rows, dinv, H, sums + 256, ctrs + 8);
    k_bnmax<<<nbSeg, 256, 0, stream>>>(H, sums + 256, g2, be2, n2s, outmax, 128);

    // conv3
    k_gemm16<<<nbG, 256, 0, stream>>>(H, WT + 32768, dinv, XWp);
    k_aggpmax<<<AGGP_GRID, 256, 0, stream>>>(XWp, begs, ends, rows, dinv, b3, n2s, outmax, ctrs + 16);
}

// Round 10
// 668.945 us; speedup vs baseline: 2.8142x; 2.8142x over previous
//
#include <hip/hip_runtime.h>
#include <hip/hip_fp16.h>

#define NN 100000
#define NE 3200000
#define SG 2048
#define OUTC 384
#define EPS 1e-5f

#define NBUK 800
#define BNODES 125
#define CAP 5120
#define TILE 4096
#define B_BUCKET 782      // ceil(NE/TILE)
#define B_GEMM 391        // ceil(NN/256)
#define LDSTRIDE 136
#define AGG_BLOCKS 3584
#define CHUNK 7           // nodes per wave (3584*4*7 = 100352 >= NN)
#define NBANK 32          // stats replication banks

typedef _Float16 f16x8 __attribute__((ext_vector_type(8)));
typedef float f32x16 __attribute__((ext_vector_type(16)));

// ---------------- init: W transpose prep + zero out/gcur/sums ----------------
__global__ void k_init(const float* __restrict__ W1, const float* __restrict__ W2,
                       const float* __restrict__ W3, __half* __restrict__ WT,
                       unsigned int* __restrict__ outz, int* __restrict__ gcur,
                       float* __restrict__ sums) {
    int g = blockIdx.x * 256 + threadIdx.x;
    int nt = gridDim.x * 256;
    for (int i = g; i < SG * OUTC; i += nt) outz[i] = 0u;
    if (g < NBUK) gcur[g] = 0;
    for (int i = g; i < 2 * NBANK * 256; i += nt) sums[i] = 0.f;
    for (int i = g; i < 3 * 16384; i += nt) {
        int m = i >> 14, idx = i & 16383;
        int k = idx >> 7, n = idx & 127;
        const float* W = m == 0 ? W1 : (m == 1 ? W2 : W3);
        WT[m * 16384 + n * 128 + k] = __float2half(W[idx]);
    }
}

// ---------------- fused stage 1: bucketA (0..781) || gemm32 unscaled (782..1172) ----------------
__device__ void bucketA_body(int* smem, int bb,
                             const int* __restrict__ erow, const int* __restrict__ ecol,
                             int* __restrict__ gcur, int* __restrict__ packed) {
    int* sc   = smem;           // 4096
    int* sr   = smem + 4096;    // 4096
    int* hist = smem + 8192;    // 1024
    int* loff = smem + 9216;    // 1024
    int* gch  = smem + 10240;   // 1024
    int* cur  = smem + 11264;   // 1024
    int* psum = smem + 12288;   // 256
    int t = threadIdx.x;
    hist[t] = 0; hist[t + 256] = 0; hist[t + 512] = 0; hist[t + 768] = 0;
    __syncthreads();
    int e0 = bb * TILE;
    int lim = NE - e0; if (lim > TILE) lim = TILE;
    for (int i = t; i < lim; i += 256) {
        int c = ecol[e0 + i];
        int r = erow[e0 + i];
        sc[i] = c; sr[i] = r;
        atomicAdd(&hist[c / BNODES], 1);
    }
    __syncthreads();
    int h0 = hist[4 * t], h1 = hist[4 * t + 1], h2 = hist[4 * t + 2], h3 = hist[4 * t + 3];
    int s = h0 + h1 + h2 + h3;
    psum[t] = s; __syncthreads();
    for (int st = 1; st < 256; st <<= 1) {
        int a = (t >= st) ? psum[t - st] : 0;
        __syncthreads();
        psum[t] += a;
        __syncthreads();
    }
    int base = psum[t] - s;
    loff[4 * t] = base;
    loff[4 * t + 1] = base + h0;
    loff[4 * t + 2] = base + h0 + h1;
    loff[4 * t + 3] = base + h0 + h1 + h2;
#pragma unroll
    for (int j = 0; j < 4; ++j) {
        int b = 4 * t + j;
        if (b < NBUK) {
            int c = hist[b];
            gch[b] = c ? atomicAdd(&gcur[b], c) : 0;
            cur[b] = loff[b];
        }
    }
    __syncthreads();
    for (int i = t; i < lim; i += 256) {
        int c = sc[i], r = sr[i];
        int b = c / BNODES;
        int lc = c - b * BNODES;
        int p = atomicAdd(&cur[b], 1);
        int rank = p - loff[b];
        if (gch[b] + rank < CAP) packed[b * CAP + gch[b] + rank] = r | (lc << 17);
    }
}

__device__ void gemm32u_body(int* smem, int gb, const float* __restrict__ A,
                             const __half* __restrict__ WTg, __half* __restrict__ C) {
    _Float16* Wl = (_Float16*)smem;
    int tid = threadIdx.x;
    for (int ch = tid; ch < 2048; ch += 256) {
        int n = ch >> 4, seg = ch & 15;
        *(uint4*)&Wl[n * LDSTRIDE + seg * 8] = *(const uint4*)(WTg + n * 128 + seg * 8);
    }
    __syncthreads();
    int wave = tid >> 6, lane = tid & 63;
    int l31 = lane & 31, lhi = lane >> 5;
    int rowbase = gb * 256 + wave * 64;
    f32x16 acc[2][4];
#pragma unroll
    for (int rt = 0; rt < 2; ++rt)
#pragma unroll
        for (int nt = 0; nt < 4; ++nt)
#pragma unroll
            for (int i = 0; i < 16; ++i) acc[rt][nt][i] = 0.f;
    int r0 = rowbase + l31;      if (r0 >= NN) r0 = NN - 1;
    int r1 = rowbase + 32 + l31; if (r1 >= NN) r1 = NN - 1;
    const float* A0 = A + (size_t)r0 * 128;
    const float* A1 = A + (size_t)r1 * 128;
#pragma unroll
    for (int ks = 0; ks < 8; ++ks) {
        int koff = ks * 16 + lhi * 8;
        float4 f0 = *(const float4*)(A0 + koff);
        float4 f1 = *(const float4*)(A0 + koff + 4);
        float4 g0 = *(const float4*)(A1 + koff);
        float4 g1 = *(const float4*)(A1 + koff + 4);
        f16x8 a0, a1;
        a0[0] = (_Float16)f0.x; a0[1] = (_Float16)f0.y; a0[2] = (_Float16)f0.z; a0[3] = (_Float16)f0.w;
        a0[4] = (_Float16)f1.x; a0[5] = (_Float16)f1.y; a0[6] = (_Float16)f1.z; a0[7] = (_Float16)f1.w;
        a1[0] = (_Float16)g0.x; a1[1] = (_Float16)g0.y; a1[2] = (_Float16)g0.z; a1[3] = (_Float16)g0.w;
        a1[4] = (_Float16)g1.x; a1[5] = (_Float16)g1.y; a1[6] = (_Float16)g1.z; a1[7] = (_Float16)g1.w;
#pragma unroll
        for (int nt = 0; nt < 4; ++nt) {
            f16x8 b = *(const f16x8*)&Wl[(nt * 32 + l31) * LDSTRIDE + ks * 16 + lhi * 8];
            acc[0][nt] = __builtin_amdgcn_mfma_f32_32x32x16_f16(a0, b, acc[0][nt], 0, 0, 0);
            acc[1][nt] = __builtin_amdgcn_mfma_f32_32x32x16_f16(a1, b, acc[1][nt], 0, 0, 0);
        }
    }
#pragma unroll
    for (int rt = 0; rt < 2; ++rt) {
#pragma unroll
        for (int r = 0; r < 16; ++r) {
            int row = rowbase + rt * 32 + (r & 3) + 8 * (r >> 2) + 4 * lhi;
            if (row < NN) {
                size_t cb = (size_t)row * 128 + l31;
                C[cb]      = __float2half(acc[rt][0][r]);
                C[cb + 32] = __float2half(acc[rt][1][r]);
                C[cb + 64] = __float2half(acc[rt][2][r]);
                C[cb + 96] = __float2half(acc[rt][3][r]);
            }
        }
    }
}

__global__ __launch_bounds__(256, 2) void k_fused1(const int* __restrict__ erow,
                                                   const int* __restrict__ ecol,
                                                   int* __restrict__ gcur,
                                                   int* __restrict__ packed,
                                                   const float* __restrict__ x,
                                                   const __half* __restrict__ WT,
                                                   __half* __restrict__ XWh) {
    __shared__ __align__(16) int smem[12544];   // 49 KB union
    int bb = blockIdx.x;
    if (bb < B_BUCKET) bucketA_body(smem, bb, erow, ecol, gcur, packed);
    else gemm32u_body(smem, bb - B_BUCKET, x, WT, XWh);
}

// ---------------- stage B: CSR build + dinv + in-place XWh row scaling ----------------
__global__ __launch_bounds__(256) void k_csrB(int* __restrict__ rows,
                                              const int* __restrict__ gcur,
                                              int* __restrict__ begs, int* __restrict__ ends,
                                              float* __restrict__ dinv,
                                              __half* __restrict__ XWh) {
    __shared__ int lin[CAP];
    __shared__ int hist[128], off[128], cur[128], psc[128];
    __shared__ float dinvl[128];
    int b = blockIdx.x, t = threadIdx.x;
    int cnt = gcur[b]; if (cnt > CAP) cnt = CAP;
    int base = b * CAP;
    for (int i = t; i < cnt; i += 256) lin[i] = rows[base + i];
    if (t < 128) hist[t] = 0;
    __syncthreads();
    for (int i = t; i < cnt; i += 256) atomicAdd(&hist[lin[i] >> 17], 1);
    __syncthreads();
    int pc = 0;
    if (t < 128) { pc = (hist[t] + 3) & ~3; psc[t] = pc; }
    __syncthreads();
    for (int st = 1; st < 128; st <<= 1) {
        int a = 0;
        if (t < 128 && t >= st) a = psc[t - st];
        __syncthreads();
        if (t < 128) psc[t] += a;
        __syncthreads();
    }
    if (t < 128) { off[t] = psc[t] - pc; cur[t] = off[t]; }
    __syncthreads();
    if (t < BNODES) {
        int n = b * BNODES + t;
        int c = hist[t];
        int bg = base + off[t];
        begs[n] = bg;
        ends[n] = bg + c;
        float dv = rsqrtf((float)(c + 1));
        dinv[n] = dv;
        dinvl[t] = dv;
        int pad = (c + 3) & ~3;
        for (int p = c; p < pad; ++p)
            if (off[t] + p < CAP) rows[base + off[t] + p] = 0;
    }
    __syncthreads();
    for (int i = t; i < cnt; i += 256) {
        int w = lin[i];
        int lc = w >> 17;
        int p = atomicAdd(&cur[lc], 1);
        if (p < CAP) rows[base + p] = w & 0x1FFFF;
    }
    // scale this bucket's 125 XWh rows by dinv (2 threads per row, 64 halves each)
    int rr = t >> 1, half = t & 1;
    if (rr < BNODES) {
        float dv = dinvl[rr];
        int n = b * BNODES + rr;
        uint4* p = (uint4*)(XWh + (size_t)n * 128) + half * 8;
#pragma unroll
        for (int j = 0; j < 8; ++j) {
            uint4 v = p[j];
            __half2* h = (__half2*)&v;
#pragma unroll
            for (int q = 0; q < 4; ++q) {
                float2 f = __half22float2(h[q]);
                h[q] = __floats2half2_rn(f.x * dv, f.y * dv);
            }
            p[j] = v;
        }
    }
}

// ---------------- MFMA GEMM (A fp16): C = dinv[row]*(A @ W), fp16 out ----------------
__global__ __launch_bounds__(256, 2) void k_gemm16(const __half* __restrict__ A,
                                                   const __half* __restrict__ WTg,
                                                   const float* __restrict__ dinv,
                                                   __half* __restrict__ C) {
    __shared__ _Float16 Wl[128 * LDSTRIDE];
    int tid = threadIdx.x;
    for (int ch = tid; ch < 2048; ch += 256) {
        int n = ch >> 4, seg = ch & 15;
        *(uint4*)&Wl[n * LDSTRIDE + seg * 8] = *(const uint4*)(WTg + n * 128 + seg * 8);
    }
    __syncthreads();
    int wave = tid >> 6, lane = tid & 63;
    int l31 = lane & 31, lhi = lane >> 5;
    int rowbase = blockIdx.x * 256 + wave * 64;
    f32x16 acc[2][4];
#pragma unroll
    for (int rt = 0; rt < 2; ++rt)
#pragma unroll
        for (int nt = 0; nt < 4; ++nt)
#pragma unroll
            for (int i = 0; i < 16; ++i) acc[rt][nt][i] = 0.f;
    int r0 = rowbase + l31;      if (r0 >= NN) r0 = NN - 1;
    int r1 = rowbase + 32 + l31; if (r1 >= NN) r1 = NN - 1;
    const f16x8* A0 = (const f16x8*)(A + (size_t)r0 * 128);
    const f16x8* A1 = (const f16x8*)(A + (size_t)r1 * 128);
#pragma unroll
    for (int ks = 0; ks < 8; ++ks) {
        f16x8 a0 = A0[ks * 2 + lhi];
        f16x8 a1 = A1[ks * 2 + lhi];
#pragma unroll
        for (int nt = 0; nt < 4; ++nt) {
            f16x8 b = *(const f16x8*)&Wl[(nt * 32 + l31) * LDSTRIDE + ks * 16 + lhi * 8];
            acc[0][nt] = __builtin_amdgcn_mfma_f32_32x32x16_f16(a0, b, acc[0][nt], 0, 0, 0);
            acc[1][nt] = __builtin_amdgcn_mfma_f32_32x32x16_f16(a1, b, acc[1][nt], 0, 0, 0);
        }
    }
#pragma unroll
    for (int rt = 0; rt < 2; ++rt) {
#pragma unroll
        for (int r = 0; r < 16; ++r) {
            int row = rowbase + rt * 32 + (r & 3) + 8 * (r >> 2) + 4 * lhi;
            if (row < NN) {
                float sc = dinv[row];
                size_t cb = (size_t)row * 128 + l31;
                C[cb]      = __float2half(acc[rt][0][r] * sc);
                C[cb + 32] = __float2half(acc[rt][1][r] * sc);
                C[cb + 64] = __float2half(acc[rt][2][r] * sc);
                C[cb + 96] = __float2half(acc[rt][3][r] * sc);
            }
        }
    }
}

// ---------------- aggregation helpers ----------------
__device__ __forceinline__ void accum8(float* acc, uint4 v) {
    float2 f;
    f = __half22float2(*(__half2*)&v.x); acc[0] += f.x; acc[1] += f.y;
    f = __half22float2(*(__half2*)&v.y); acc[2] += f.x; acc[3] += f.y;
    f = __half22float2(*(__half2*)&v.z); acc[4] += f.x; acc[5] += f.y;
    f = __half22float2(*(__half2*)&v.w); acc[6] += f.x; acc[7] += f.y;
}
__device__ __forceinline__ void accum8w(float* acc, uint4 v, float w) {
    float2 f;
    f = __half22float2(*(__half2*)&v.x); acc[0] = fmaf(w, f.x, acc[0]); acc[1] = fmaf(w, f.y, acc[1]);
    f = __half22float2(*(__half2*)&v.y); acc[2] = fmaf(w, f.x, acc[2]); acc[3] = fmaf(w, f.y, acc[3]);
    f = __half22float2(*(__half2*)&v.z); acc[4] = fmaf(w, f.x, acc[4]); acc[5] = fmaf(w, f.y, acc[5]);
    f = __half22float2(*(__half2*)&v.w); acc[6] = fmaf(w, f.x, acc[6]); acc[7] = fmaf(w, f.y, acc[7]);
}

// node aggregation core: 16 B/lane gathers, 4 edges/instr; result in quad0 lanes
__device__ __forceinline__ void agg_node(const uint4* __restrict__ XW4,
                                         const int* __restrict__ rows,
                                         int n, int beg, int end, int quad, int li,
                                         float* acc) {
#pragma unroll
    for (int j = 0; j < 8; ++j) acc[j] = 0.f;
    if (quad == 0) {
        uint4 sv = XW4[(size_t)n * 16 + li];
        accum8(acc, sv);
    }
    int e = beg;
    for (; e + 32 <= end; e += 32) {
        int4 ia = *(const int4*)(rows + e + 4 * quad);
        int4 ib = *(const int4*)(rows + e + 16 + 4 * quad);
        uint4 v0 = XW4[(size_t)ia.x * 16 + li];
        uint4 v1 = XW4[(size_t)ia.y * 16 + li];
        uint4 v2 = XW4[(size_t)ia.z * 16 + li];
        uint4 v3 = XW4[(size_t)ia.w * 16 + li];
        uint4 v4 = XW4[(size_t)ib.x * 16 + li];
        uint4 v5 = XW4[(size_t)ib.y * 16 + li];
        uint4 v6 = XW4[(size_t)ib.z * 16 + li];
        uint4 v7 = XW4[(size_t)ib.w * 16 + li];
        accum8(acc, v0); accum8(acc, v1); accum8(acc, v2); accum8(acc, v3);
        accum8(acc, v4); accum8(acc, v5); accum8(acc, v6); accum8(acc, v7);
    }
    for (; e + 16 <= end; e += 16) {
        int4 ia = *(const int4*)(rows + e + 4 * quad);
        uint4 v0 = XW4[(size_t)ia.x * 16 + li];
        uint4 v1 = XW4[(size_t)ia.y * 16 + li];
        uint4 v2 = XW4[(size_t)ia.z * 16 + li];
        uint4 v3 = XW4[(size_t)ia.w * 16 + li];
        accum8(acc, v0); accum8(acc, v1); accum8(acc, v2); accum8(acc, v3);
    }
    if (e < end) {
        int rem = end - e;
        int qb = 4 * quad;
        int4 it = make_int4(0, 0, 0, 0);
        if (qb < rem) it = *(const int4*)(rows + e + qb);
        uint4 v0 = XW4[(size_t)it.x * 16 + li];
        uint4 v1 = XW4[(size_t)it.y * 16 + li];
        uint4 v2 = XW4[(size_t)it.z * 16 + li];
        uint4 v3 = XW4[(size_t)it.w * 16 + li];
        accum8w(acc, v0, (qb + 0 < rem) ? 1.f : 0.f);
        accum8w(acc, v1, (qb + 1 < rem) ? 1.f : 0.f);
        accum8w(acc, v2, (qb + 2 < rem) ? 1.f : 0.f);
        accum8w(acc, v3, (qb + 3 < rem) ? 1.f : 0.f);
    }
#pragma unroll
    for (int j = 0; j < 8; ++j) {
        acc[j] += __shfl_xor(acc[j], 16, 64);
        acc[j] += __shfl_xor(acc[j], 32, 64);
    }
}

// ---------------- agg + fused column stats (conv1/conv2), banked sums ----------------
__global__ __launch_bounds__(256) void k_agghs(const __half* __restrict__ XWh,
                                               const int* __restrict__ begs,
                                               const int* __restrict__ ends,
                                               const int* __restrict__ rows,
                                               const float* __restrict__ dinv,
                                               __half* __restrict__ outh,
                                               float* __restrict__ sums) {
    __shared__ float sred[4][256];
    int wave = threadIdx.x >> 6, lane = threadIdx.x & 63;
    int quad = lane >> 4, li = lane & 15;
    const uint4* XW4 = (const uint4*)XWh;
    int wid = blockIdx.x * 4 + wave;
    int n0 = wid * CHUNK;
    int n1 = n0 + CHUNK; if (n1 > NN) n1 = NN;
    float ssum[8] = {}, sqsum[8] = {};
    for (int n = n0; n < n1; ++n) {
        float acc[8];
        agg_node(XW4, rows, n, begs[n], ends[n], quad, li, acc);
        if (quad == 0) {
            float dn = dinv[n];
            __half2 hh[4];
#pragma unroll
            for (int j = 0; j < 8; ++j) {
                float v = acc[j] * dn;
                acc[j] = v;
                ssum[j] += v;
                sqsum[j] += v * v;
            }
            hh[0] = __floats2half2_rn(acc[0], acc[1]);
            hh[1] = __floats2half2_rn(acc[2], acc[3]);
            hh[2] = __floats2half2_rn(acc[4], acc[5]);
            hh[3] = __floats2half2_rn(acc[6], acc[7]);
            *(uint4*)(outh + (size_t)n * 128 + li * 8) = *(uint4*)hh;
        }
    }
    if (quad == 0) {
#pragma unroll
        for (int j = 0; j < 8; ++j) {
            sred[wave][li * 8 + j] = ssum[j];
            sred[wave][128 + li * 8 + j] = sqsum[j];
        }
    }
    __syncthreads();
    int t = threadIdx.x;
    float tot = sred[0][t] + sred[1][t] + sred[2][t] + sred[3][t];
    atomicAdd(&sums[(blockIdx.x & (NBANK - 1)) * 256 + t], tot);
}

// ---------------- agg + fused bias/ReLU/segment-max (conv3), no H write ----------------
__global__ __launch_bounds__(256) void k_agghmax(const __half* __restrict__ XWh,
                                                 const int* __restrict__ begs,
                                                 const int* __restrict__ ends,
                                                 const int* __restrict__ rows,
                                                 const float* __restrict__ dinv,
                                                 const float* __restrict__ b3,
                                                 const int* __restrict__ n2s,
                                                 unsigned int* __restrict__ outmax) {
    int wave = threadIdx.x >> 6, lane = threadIdx.x & 63;
    int quad = lane >> 4, li = lane & 15;
    const uint4* XW4 = (const uint4*)XWh;
    int wid = blockIdx.x * 4 + wave;
    int n0 = wid * CHUNK;
    int n1 = n0 + CHUNK; if (n1 > NN) n1 = NN;
    float4 bz0 = *(const float4*)(b3 + li * 8);
    float4 bz1 = *(const float4*)(b3 + li * 8 + 4);
    float bias[8] = {bz0.x, bz0.y, bz0.z, bz0.w, bz1.x, bz1.y, bz1.z, bz1.w};
    int cur = -1;
    float runmax[8];
    for (int n = n0; n < n1; ++n) {
        float acc[8];
        agg_node(XW4, rows, n, begs[n], ends[n], quad, li, acc);
        float dn = dinv[n];
        int sg = n2s[n];
        if (sg != cur) {
            if (cur >= 0 && quad == 0) {
#pragma unroll
                for (int j = 0; j < 8; ++j)
                    atomicMax(&outmax[cur * OUTC + 256 + li * 8 + j], __float_as_uint(runmax[j]));
            }
            cur = sg;
#pragma unroll
            for (int j = 0; j < 8; ++j) runmax[j] = fmaxf(acc[j] * dn + bias[j], 0.f);
        } else {
#pragma unroll
            for (int j = 0; j < 8; ++j) runmax[j] = fmaxf(runmax[j], fmaxf(acc[j] * dn + bias[j], 0.f));
        }
    }
    if (cur >= 0 && quad == 0) {
#pragma unroll
        for (int j = 0; j < 8; ++j)
            atomicMax(&outmax[cur * OUTC + 256 + li * 8 + j], __float_as_uint(runmax[j]));
    }
}

// ---------------- BN + ReLU (in-place fp16 h) + sorted segment-max, banked sums ----------------
__global__ void k_bnmax(__half* __restrict__ buf, const float* __restrict__ sums,
                        const float* __restrict__ g, const float* __restrict__ be,
                        const int* __restrict__ n2s,
                        unsigned int* __restrict__ outmax, int colOff) {
    int c = threadIdx.x & 127;
    int rg = threadIdx.x >> 7;
    int n0 = blockIdx.x * 64;
    int nEnd = n0 + 64; if (nEnd > NN) nEnd = NN;
    float s = 0.f, q = 0.f;
#pragma unroll
    for (int b = 0; b < NBANK; ++b) {
        s += sums[b * 256 + c];
        q += sums[b * 256 + 128 + c];
    }
    float mean = s * (1.0f / NN);
    float inv = rsqrtf(q * (1.0f / NN) - mean * mean + EPS) * g[c];
    float sc = inv, sh = be[c] - mean * inv;
    int cur = -1; float runmax = 0.f;
    for (int n = n0 + rg; n < nEnd; n += 2) {
        float v = fmaxf(__half2float(buf[(size_t)n * 128 + c]) * sc + sh, 0.f);
        buf[(size_t)n * 128 + c] = __float2half(v);
        int sg = n2s[n];
        if (sg != cur) {
            if (cur >= 0) atomicMax(&outmax[cur * OUTC + colOff + c], __float_as_uint(runmax));
            cur = sg; runmax = v;
        } else {
            runmax = fmaxf(runmax, v);
        }
    }
    if (cur >= 0) atomicMax(&outmax[cur * OUTC + colOff + c], __float_as_uint(runmax));
}

// ---------------- launch ----------------
extern "C" void kernel_launch(void* const* d_in, const int* in_sizes, int n_in,
                              void* d_out, int out_size, void* d_ws, size_t ws_size,
                              hipStream_t stream) {
    const float* x   = (const float*)d_in[0];
    const int*   ei  = (const int*)d_in[1];
    const int*   n2s = (const int*)d_in[2];
    const float* W1  = (const float*)d_in[3];
    const float* g1  = (const float*)d_in[5];
    const float* be1 = (const float*)d_in[6];
    const float* W2  = (const float*)d_in[7];
    const float* g2  = (const float*)d_in[9];
    const float* be2 = (const float*)d_in[10];
    const float* W3  = (const float*)d_in[11];
    const float* b3  = (const float*)d_in[12];

    __half* H    = (__half*)d_ws;                        // NN*128 fp16 (agg/h)
    __half* XWh  = H + (size_t)NN * 128;                 // NN*128 fp16
    __half* WT   = XWh + (size_t)NN * 128;               // 3*16384 fp16
    int* rows    = (int*)(WT + 3 * 16384);               // NBUK*CAP
    int* begs    = rows + (size_t)NBUK * CAP;            // NN
    int* ends    = begs + NN;                            // NN
    float* dinv  = (float*)(ends + NN);                  // NN
    int* gcur    = (int*)(dinv + NN);                    // NBUK
    float* sums  = (float*)(gcur + NBUK);                // 2 * NBANK * 256

    const int* erow = ei;
    const int* ecol = ei + NE;
    unsigned int* outmax = (unsigned int*)d_out;
    int nbSeg = (NN + 63) / 64;       // 1563
    int nbG = (NN + 255) / 256;       // 391

    k_init<<<512, 256, 0, stream>>>(W1, W2, W3, WT, outmax, gcur, sums);
    k_fused1<<<B_BUCKET + B_GEMM, 256, 0, stream>>>(erow, ecol, gcur, rows, x, WT, XWh);
    k_csrB<<<NBUK, 256, 0, stream>>>(rows, gcur, begs, ends, dinv, XWh);

    // conv1
    k_agghs<<<AGG_BLOCKS, 256, 0, stream>>>(XWh, begs, ends, rows, dinv, H, sums);
    k_bnmax<<<nbSeg, 256, 0, stream>>>(H, sums, g1, be1, n2s, outmax, 0);

    // conv2
    k_gemm16<<<nbG, 256, 0, stream>>>(H, WT + 16384, dinv, XWh);
    k_agghs<<<AGG_BLOCKS, 256, 0, stream>>>(XWh, begs, ends, rows, dinv, H, sums + NBANK * 256);
    k_bnmax<<<nbSeg, 256, 0, stream>>>(H, sums + NBANK * 256, g2, be2, n2s, outmax, 128);

    // conv3
    k_gemm16<<<nbG, 256, 0, stream>>>(H, WT + 32768, dinv, XWh);
    k_agghmax<<<AGG_BLOCKS, 256, 0, stream>>>(XWh, begs, ends, rows, dinv, b3, n2s, outmax);
}

// Round 11
// 646.927 us; speedup vs baseline: 2.9100x; 1.0340x over previous
//
#include <hip/hip_runtime.h>
#include <hip/hip_fp16.h>

#define NN 100000
#define NE 3200000
#define SG 2048
#define OUTC 384
#define EPS 1e-5f

#define NBUK 800
#define BNODES 125
#define CAP 5120
#define TILE 4096
#define B_BUCKET 782      // ceil(NE/TILE)
#define B_GEMM 391        // ceil(NN/256)
#define B_MAX 1563        // ceil(NN/64)
#define LDSTRIDE 136
#define AGG_BLOCKS 3584
#define CHUNK 7           // nodes per wave (3584*4*7 = 100352 >= NN)
#define NBANK 32          // stats replication banks

typedef _Float16 f16x8 __attribute__((ext_vector_type(8)));
typedef float f32x16 __attribute__((ext_vector_type(16)));
typedef float floatx2 __attribute__((ext_vector_type(2)));

// ---------------- init: W transpose prep + zero out/gcur/sums ----------------
__global__ void k_init(const float* __restrict__ W1, const float* __restrict__ W2,
                       const float* __restrict__ W3, __half* __restrict__ WT,
                       unsigned int* __restrict__ outz, int* __restrict__ gcur,
                       float* __restrict__ sums) {
    int g = blockIdx.x * 256 + threadIdx.x;
    int nt = gridDim.x * 256;
    for (int i = g; i < SG * OUTC; i += nt) outz[i] = 0u;
    if (g < NBUK) gcur[g] = 0;
    for (int i = g; i < 2 * NBANK * 256; i += nt) sums[i] = 0.f;
    for (int i = g; i < 3 * 16384; i += nt) {
        int m = i >> 14, idx = i & 16383;
        int k = idx >> 7, n = idx & 127;
        const float* W = m == 0 ? W1 : (m == 1 ? W2 : W3);
        WT[m * 16384 + n * 128 + k] = __float2half(W[idx]);
    }
}

// ---------------- fused stage 1: bucketA (0..781) || gemm32 unscaled (782..1172) ----------------
__device__ void bucketA_body(int* smem, int bb,
                             const int* __restrict__ erow, const int* __restrict__ ecol,
                             int* __restrict__ gcur, int* __restrict__ packed) {
    int* sc   = smem;           // 4096
    int* sr   = smem + 4096;    // 4096
    int* hist = smem + 8192;    // 1024
    int* loff = smem + 9216;    // 1024
    int* gch  = smem + 10240;   // 1024
    int* cur  = smem + 11264;   // 1024
    int* psum = smem + 12288;   // 256
    int t = threadIdx.x;
    hist[t] = 0; hist[t + 256] = 0; hist[t + 512] = 0; hist[t + 768] = 0;
    __syncthreads();
    int e0 = bb * TILE;
    int lim = NE - e0; if (lim > TILE) lim = TILE;
    for (int i = t; i < lim; i += 256) {
        int c = ecol[e0 + i];
        int r = erow[e0 + i];
        sc[i] = c; sr[i] = r;
        atomicAdd(&hist[c / BNODES], 1);
    }
    __syncthreads();
    int h0 = hist[4 * t], h1 = hist[4 * t + 1], h2 = hist[4 * t + 2], h3 = hist[4 * t + 3];
    int s = h0 + h1 + h2 + h3;
    psum[t] = s; __syncthreads();
    for (int st = 1; st < 256; st <<= 1) {
        int a = (t >= st) ? psum[t - st] : 0;
        __syncthreads();
        psum[t] += a;
        __syncthreads();
    }
    int base = psum[t] - s;
    loff[4 * t] = base;
    loff[4 * t + 1] = base + h0;
    loff[4 * t + 2] = base + h0 + h1;
    loff[4 * t + 3] = base + h0 + h1 + h2;
#pragma unroll
    for (int j = 0; j < 4; ++j) {
        int b = 4 * t + j;
        if (b < NBUK) {
            int c = hist[b];
            gch[b] = c ? atomicAdd(&gcur[b], c) : 0;
            cur[b] = loff[b];
        }
    }
    __syncthreads();
    for (int i = t; i < lim; i += 256) {
        int c = sc[i], r = sr[i];
        int b = c / BNODES;
        int lc = c - b * BNODES;
        int p = atomicAdd(&cur[b], 1);
        int rank = p - loff[b];
        if (gch[b] + rank < CAP) packed[b * CAP + gch[b] + rank] = r | (lc << 17);
    }
}

__device__ void gemm32u_body(int* smem, int gb, const float* __restrict__ A,
                             const __half* __restrict__ WTg, __half* __restrict__ C) {
    _Float16* Wl = (_Float16*)smem;
    int tid = threadIdx.x;
    for (int ch = tid; ch < 2048; ch += 256) {
        int n = ch >> 4, seg = ch & 15;
        *(uint4*)&Wl[n * LDSTRIDE + seg * 8] = *(const uint4*)(WTg + n * 128 + seg * 8);
    }
    __syncthreads();
    int wave = tid >> 6, lane = tid & 63;
    int l31 = lane & 31, lhi = lane >> 5;
    int rowbase = gb * 256 + wave * 64;
    f32x16 acc[2][4];
#pragma unroll
    for (int rt = 0; rt < 2; ++rt)
#pragma unroll
        for (int nt = 0; nt < 4; ++nt)
#pragma unroll
            for (int i = 0; i < 16; ++i) acc[rt][nt][i] = 0.f;
    int r0 = rowbase + l31;      if (r0 >= NN) r0 = NN - 1;
    int r1 = rowbase + 32 + l31; if (r1 >= NN) r1 = NN - 1;
    const float* A0 = A + (size_t)r0 * 128;
    const float* A1 = A + (size_t)r1 * 128;
#pragma unroll
    for (int ks = 0; ks < 8; ++ks) {
        int koff = ks * 16 + lhi * 8;
        float4 f0 = *(const float4*)(A0 + koff);
        float4 f1 = *(const float4*)(A0 + koff + 4);
        float4 g0 = *(const float4*)(A1 + koff);
        float4 g1 = *(const float4*)(A1 + koff + 4);
        f16x8 a0, a1;
        a0[0] = (_Float16)f0.x; a0[1] = (_Float16)f0.y; a0[2] = (_Float16)f0.z; a0[3] = (_Float16)f0.w;
        a0[4] = (_Float16)f1.x; a0[5] = (_Float16)f1.y; a0[6] = (_Float16)f1.z; a0[7] = (_Float16)f1.w;
        a1[0] = (_Float16)g0.x; a1[1] = (_Float16)g0.y; a1[2] = (_Float16)g0.z; a1[3] = (_Float16)g0.w;
        a1[4] = (_Float16)g1.x; a1[5] = (_Float16)g1.y; a1[6] = (_Float16)g1.z; a1[7] = (_Float16)g1.w;
#pragma unroll
        for (int nt = 0; nt < 4; ++nt) {
            f16x8 b = *(const f16x8*)&Wl[(nt * 32 + l31) * LDSTRIDE + ks * 16 + lhi * 8];
            acc[0][nt] = __builtin_amdgcn_mfma_f32_32x32x16_f16(a0, b, acc[0][nt], 0, 0, 0);
            acc[1][nt] = __builtin_amdgcn_mfma_f32_32x32x16_f16(a1, b, acc[1][nt], 0, 0, 0);
        }
    }
#pragma unroll
    for (int rt = 0; rt < 2; ++rt) {
#pragma unroll
        for (int r = 0; r < 16; ++r) {
            int row = rowbase + rt * 32 + (r & 3) + 8 * (r >> 2) + 4 * lhi;
            if (row < NN) {
                size_t cb = (size_t)row * 128 + l31;
                C[cb]      = __float2half(acc[rt][0][r]);
                C[cb + 32] = __float2half(acc[rt][1][r]);
                C[cb + 64] = __float2half(acc[rt][2][r]);
                C[cb + 96] = __float2half(acc[rt][3][r]);
            }
        }
    }
}

__global__ __launch_bounds__(256, 2) void k_fused1(const int* __restrict__ erow,
                                                   const int* __restrict__ ecol,
                                                   int* __restrict__ gcur,
                                                   int* __restrict__ packed,
                                                   const float* __restrict__ x,
                                                   const __half* __restrict__ WT,
                                                   __half* __restrict__ XWh) {
    __shared__ __align__(16) int smem[12544];   // 49 KB union
    int bb = blockIdx.x;
    if (bb < B_BUCKET) bucketA_body(smem, bb, erow, ecol, gcur, packed);
    else gemm32u_body(smem, bb - B_BUCKET, x, WT, XWh);
}

// ---------------- stage B: CSR build + dinv + in-place XWh row scaling ----------------
__global__ __launch_bounds__(256) void k_csrB(int* __restrict__ rows,
                                              const int* __restrict__ gcur,
                                              int* __restrict__ begs, int* __restrict__ ends,
                                              float* __restrict__ dinv,
                                              __half* __restrict__ XWh) {
    __shared__ int lin[CAP];
    __shared__ int hist[128], off[128], cur[128], psc[128];
    __shared__ float dinvl[128];
    int b = blockIdx.x, t = threadIdx.x;
    int cnt = gcur[b]; if (cnt > CAP) cnt = CAP;
    int base = b * CAP;
    for (int i = t; i < cnt; i += 256) lin[i] = rows[base + i];
    if (t < 128) hist[t] = 0;
    __syncthreads();
    for (int i = t; i < cnt; i += 256) atomicAdd(&hist[lin[i] >> 17], 1);
    __syncthreads();
    int pc = 0;
    if (t < 128) { pc = (hist[t] + 3) & ~3; psc[t] = pc; }
    __syncthreads();
    for (int st = 1; st < 128; st <<= 1) {
        int a = 0;
        if (t < 128 && t >= st) a = psc[t - st];
        __syncthreads();
        if (t < 128) psc[t] += a;
        __syncthreads();
    }
    if (t < 128) { off[t] = psc[t] - pc; cur[t] = off[t]; }
    __syncthreads();
    if (t < BNODES) {
        int n = b * BNODES + t;
        int c = hist[t];
        int bg = base + off[t];
        begs[n] = bg;
        ends[n] = bg + c;
        float dv = rsqrtf((float)(c + 1));
        dinv[n] = dv;
        dinvl[t] = dv;
        int pad = (c + 3) & ~3;
        for (int p = c; p < pad; ++p)
            if (off[t] + p < CAP) rows[base + off[t] + p] = 0;
    }
    __syncthreads();
    for (int i = t; i < cnt; i += 256) {
        int w = lin[i];
        int lc = w >> 17;
        int p = atomicAdd(&cur[lc], 1);
        if (p < CAP) rows[base + p] = w & 0x1FFFF;
    }
    // scale this bucket's 125 XWh rows by dinv (2 threads per row, 64 halves each)
    int rr = t >> 1, half = t & 1;
    if (rr < BNODES) {
        float dv = dinvl[rr];
        int n = b * BNODES + rr;
        uint4* p = (uint4*)(XWh + (size_t)n * 128) + half * 8;
#pragma unroll
        for (int j = 0; j < 8; ++j) {
            uint4 v = p[j];
            __half2* h = (__half2*)&v;
#pragma unroll
            for (int q = 0; q < 4; ++q) {
                float2 f = __half22float2(h[q]);
                h[q] = __floats2half2_rn(f.x * dv, f.y * dv);
            }
            p[j] = v;
        }
    }
}

// ---------------- aggregation helpers (fp16 payload) ----------------
__device__ __forceinline__ void accum8(float* acc, uint4 v) {
    float2 f;
    f = __half22float2(*(__half2*)&v.x); acc[0] += f.x; acc[1] += f.y;
    f = __half22float2(*(__half2*)&v.y); acc[2] += f.x; acc[3] += f.y;
    f = __half22float2(*(__half2*)&v.z); acc[4] += f.x; acc[5] += f.y;
    f = __half22float2(*(__half2*)&v.w); acc[6] += f.x; acc[7] += f.y;
}
__device__ __forceinline__ void accum8w(float* acc, uint4 v, float w) {
    float2 f;
    f = __half22float2(*(__half2*)&v.x); acc[0] = fmaf(w, f.x, acc[0]); acc[1] = fmaf(w, f.y, acc[1]);
    f = __half22float2(*(__half2*)&v.y); acc[2] = fmaf(w, f.x, acc[2]); acc[3] = fmaf(w, f.y, acc[3]);
    f = __half22float2(*(__half2*)&v.z); acc[4] = fmaf(w, f.x, acc[4]); acc[5] = fmaf(w, f.y, acc[5]);
    f = __half22float2(*(__half2*)&v.w); acc[6] = fmaf(w, f.x, acc[6]); acc[7] = fmaf(w, f.y, acc[7]);
}

__device__ __forceinline__ void agg_node(const uint4* __restrict__ XW4,
                                         const int* __restrict__ rows,
                                         int n, int beg, int end, int quad, int li,
                                         float* acc) {
#pragma unroll
    for (int j = 0; j < 8; ++j) acc[j] = 0.f;
    if (quad == 0) {
        uint4 sv = XW4[(size_t)n * 16 + li];
        accum8(acc, sv);
    }
    int e = beg;
    for (; e + 32 <= end; e += 32) {
        int4 ia = *(const int4*)(rows + e + 4 * quad);
        int4 ib = *(const int4*)(rows + e + 16 + 4 * quad);
        uint4 v0 = XW4[(size_t)ia.x * 16 + li];
        uint4 v1 = XW4[(size_t)ia.y * 16 + li];
        uint4 v2 = XW4[(size_t)ia.z * 16 + li];
        uint4 v3 = XW4[(size_t)ia.w * 16 + li];
        uint4 v4 = XW4[(size_t)ib.x * 16 + li];
        uint4 v5 = XW4[(size_t)ib.y * 16 + li];
        uint4 v6 = XW4[(size_t)ib.z * 16 + li];
        uint4 v7 = XW4[(size_t)ib.w * 16 + li];
        accum8(acc, v0); accum8(acc, v1); accum8(acc, v2); accum8(acc, v3);
        accum8(acc, v4); accum8(acc, v5); accum8(acc, v6); accum8(acc, v7);
    }
    for (; e + 16 <= end; e += 16) {
        int4 ia = *(const int4*)(rows + e + 4 * quad);
        uint4 v0 = XW4[(size_t)ia.x * 16 + li];
        uint4 v1 = XW4[(size_t)ia.y * 16 + li];
        uint4 v2 = XW4[(size_t)ia.z * 16 + li];
        uint4 v3 = XW4[(size_t)ia.w * 16 + li];
        accum8(acc, v0); accum8(acc, v1); accum8(acc, v2); accum8(acc, v3);
    }
    if (e < end) {
        int rem = end - e;
        int qb = 4 * quad;
        int4 it = make_int4(0, 0, 0, 0);
        if (qb < rem) it = *(const int4*)(rows + e + qb);
        uint4 v0 = XW4[(size_t)it.x * 16 + li];
        uint4 v1 = XW4[(size_t)it.y * 16 + li];
        uint4 v2 = XW4[(size_t)it.z * 16 + li];
        uint4 v3 = XW4[(size_t)it.w * 16 + li];
        accum8w(acc, v0, (qb + 0 < rem) ? 1.f : 0.f);
        accum8w(acc, v1, (qb + 1 < rem) ? 1.f : 0.f);
        accum8w(acc, v2, (qb + 2 < rem) ? 1.f : 0.f);
        accum8w(acc, v3, (qb + 3 < rem) ? 1.f : 0.f);
    }
#pragma unroll
    for (int j = 0; j < 8; ++j) {
        acc[j] += __shfl_xor(acc[j], 16, 64);
        acc[j] += __shfl_xor(acc[j], 32, 64);
    }
}

// ---------------- agg + fused column stats (conv1/conv2): writes RAW a (fp16) ----------------
__global__ __launch_bounds__(256) void k_agghs(const __half* __restrict__ XWh,
                                               const int* __restrict__ begs,
                                               const int* __restrict__ ends,
                                               const int* __restrict__ rows,
                                               const float* __restrict__ dinv,
                                               __half* __restrict__ outA,
                                               float* __restrict__ sums) {
    __shared__ float sred[4][256];
    int wave = threadIdx.x >> 6, lane = threadIdx.x & 63;
    int quad = lane >> 4, li = lane & 15;
    const uint4* XW4 = (const uint4*)XWh;
    int wid = blockIdx.x * 4 + wave;
    int n0 = wid * CHUNK;
    int n1 = n0 + CHUNK; if (n1 > NN) n1 = NN;
    float ssum[8] = {}, sqsum[8] = {};
    for (int n = n0; n < n1; ++n) {
        float acc[8];
        agg_node(XW4, rows, n, begs[n], ends[n], quad, li, acc);
        if (quad == 0) {
            float dn = dinv[n];
            __half2 hh[4];
#pragma unroll
            for (int j = 0; j < 8; ++j) {
                float v = acc[j] * dn;
                acc[j] = v;
                ssum[j] += v;
                sqsum[j] += v * v;
            }
            hh[0] = __floats2half2_rn(acc[0], acc[1]);
            hh[1] = __floats2half2_rn(acc[2], acc[3]);
            hh[2] = __floats2half2_rn(acc[4], acc[5]);
            hh[3] = __floats2half2_rn(acc[6], acc[7]);
            *(uint4*)(outA + (size_t)n * 128 + li * 8) = *(uint4*)hh;
        }
    }
    if (quad == 0) {
#pragma unroll
        for (int j = 0; j < 8; ++j) {
            sred[wave][li * 8 + j] = ssum[j];
            sred[wave][128 + li * 8 + j] = sqsum[j];
        }
    }
    __syncthreads();
    int t = threadIdx.x;
    float tot = sred[0][t] + sred[1][t] + sred[2][t] + sred[3][t];
    atomicAdd(&sums[(blockIdx.x & (NBANK - 1)) * 256 + t], tot);
}

// ---------------- fused stage 2: gemm16bn (0..390) || maxonly (391..1953) ----------------
// h = relu(a*sc + sh) computed on the fly from raw a + banked sums.
// FP8OUT=1: emit prescaled fp8-e4m3 rows (conv3 gather payload).
template <int FP8OUT>
__global__ __launch_bounds__(256, 2) void k_fused2(const __half* __restrict__ A,
                                                   const float* __restrict__ sums,
                                                   const float* __restrict__ g,
                                                   const float* __restrict__ be,
                                                   const __half* __restrict__ WTg,
                                                   const float* __restrict__ dinv,
                                                   const int* __restrict__ n2s,
                                                   unsigned int* __restrict__ outmax,
                                                   int colOff,
                                                   void* __restrict__ Cout) {
    __shared__ _Float16 Wl[128 * LDSTRIDE];
    __shared__ float scL[128], shL[128];
    int tid = threadIdx.x;
    if (tid < 128) {
        float s = 0.f, q = 0.f;
#pragma unroll
        for (int b = 0; b < NBANK; ++b) {
            s += sums[b * 256 + tid];
            q += sums[b * 256 + 128 + tid];
        }
        float mean = s * (1.0f / NN);
        float inv = rsqrtf(q * (1.0f / NN) - mean * mean + EPS) * g[tid];
        scL[tid] = inv;
        shL[tid] = be[tid] - mean * inv;
    }
    if (blockIdx.x < B_GEMM) {
        for (int ch = tid; ch < 2048; ch += 256) {
            int n = ch >> 4, seg = ch & 15;
            *(uint4*)&Wl[n * LDSTRIDE + seg * 8] = *(const uint4*)(WTg + n * 128 + seg * 8);
        }
        __syncthreads();
        int wave = tid >> 6, lane = tid & 63;
        int l31 = lane & 31, lhi = lane >> 5;
        int rowbase = blockIdx.x * 256 + wave * 64;
        f32x16 acc[2][4];
#pragma unroll
        for (int rt = 0; rt < 2; ++rt)
#pragma unroll
            for (int nt = 0; nt < 4; ++nt)
#pragma unroll
                for (int i = 0; i < 16; ++i) acc[rt][nt][i] = 0.f;
        int r0 = rowbase + l31;      if (r0 >= NN) r0 = NN - 1;
        int r1 = rowbase + 32 + l31; if (r1 >= NN) r1 = NN - 1;
        const f16x8* A0 = (const f16x8*)(A + (size_t)r0 * 128);
        const f16x8* A1 = (const f16x8*)(A + (size_t)r1 * 128);
#pragma unroll
        for (int ks = 0; ks < 8; ++ks) {
            int koff = ks * 16 + lhi * 8;
            float4 sc0 = *(const float4*)&scL[koff];
            float4 sc1 = *(const float4*)&scL[koff + 4];
            float4 sh0 = *(const float4*)&shL[koff];
            float4 sh1 = *(const float4*)&shL[koff + 4];
            float scv[8] = {sc0.x, sc0.y, sc0.z, sc0.w, sc1.x, sc1.y, sc1.z, sc1.w};
            float shv[8] = {sh0.x, sh0.y, sh0.z, sh0.w, sh1.x, sh1.y, sh1.z, sh1.w};
            f16x8 ra0 = A0[ks * 2 + lhi];
            f16x8 ra1 = A1[ks * 2 + lhi];
            f16x8 a0, a1;
#pragma unroll
            for (int j = 0; j < 8; ++j) {
                a0[j] = (_Float16)fmaxf((float)ra0[j] * scv[j] + shv[j], 0.f);
                a1[j] = (_Float16)fmaxf((float)ra1[j] * scv[j] + shv[j], 0.f);
            }
#pragma unroll
            for (int nt = 0; nt < 4; ++nt) {
                f16x8 b = *(const f16x8*)&Wl[(nt * 32 + l31) * LDSTRIDE + ks * 16 + lhi * 8];
                acc[0][nt] = __builtin_amdgcn_mfma_f32_32x32x16_f16(a0, b, acc[0][nt], 0, 0, 0);
                acc[1][nt] = __builtin_amdgcn_mfma_f32_32x32x16_f16(a1, b, acc[1][nt], 0, 0, 0);
            }
        }
#pragma unroll
        for (int rt = 0; rt < 2; ++rt) {
#pragma unroll
            for (int r = 0; r < 16; ++r) {
                int row = rowbase + rt * 32 + (r & 3) + 8 * (r >> 2) + 4 * lhi;
                if (row < NN) {
                    float sc = dinv[row];
                    if (FP8OUT) {
                        unsigned char* C8 = (unsigned char*)Cout;
                        size_t cb = (size_t)row * 128 + l31;
#pragma unroll
                        for (int nt = 0; nt < 4; ++nt) {
                            float v = acc[rt][nt][r] * sc;
                            int enc = __builtin_amdgcn_cvt_pk_fp8_f32(v, v, 0, false);
                            C8[cb + nt * 32] = (unsigned char)(enc & 0xFF);
                        }
                    } else {
                        __half* C = (__half*)Cout;
                        size_t cb = (size_t)row * 128 + l31;
                        C[cb]      = __float2half(acc[rt][0][r] * sc);
                        C[cb + 32] = __float2half(acc[rt][1][r] * sc);
                        C[cb + 64] = __float2half(acc[rt][2][r] * sc);
                        C[cb + 96] = __float2half(acc[rt][3][r] * sc);
                    }
                }
            }
        }
    } else {
        __syncthreads();
        int b2 = blockIdx.x - B_GEMM;
        int c = tid & 127;
        int rg = tid >> 7;
        int n0 = b2 * 64;
        int nEnd = n0 + 64; if (nEnd > NN) nEnd = NN;
        float sc = scL[c], sh = shL[c];
        int cur = -1; float runmax = 0.f;
        for (int n = n0 + rg; n < nEnd; n += 2) {
            float v = fmaxf(__half2float(A[(size_t)n * 128 + c]) * sc + sh, 0.f);
            int sg = n2s[n];
            if (sg != cur) {
                if (cur >= 0) atomicMax(&outmax[cur * OUTC + colOff + c], __float_as_uint(runmax));
                cur = sg; runmax = v;
            } else {
                runmax = fmaxf(runmax, v);
            }
        }
        if (cur >= 0) atomicMax(&outmax[cur * OUTC + colOff + c], __float_as_uint(runmax));
    }
}

// ---------------- fp8 aggregation core (conv3) ----------------
__device__ __forceinline__ void accum8f8(float* acc, uint2 v) {
    floatx2 f;
    f = __builtin_amdgcn_cvt_pk_f32_fp8((int)v.x, false); acc[0] += f.x; acc[1] += f.y;
    f = __builtin_amdgcn_cvt_pk_f32_fp8((int)v.x, true);  acc[2] += f.x; acc[3] += f.y;
    f = __builtin_amdgcn_cvt_pk_f32_fp8((int)v.y, false); acc[4] += f.x; acc[5] += f.y;
    f = __builtin_amdgcn_cvt_pk_f32_fp8((int)v.y, true);  acc[6] += f.x; acc[7] += f.y;
}
__device__ __forceinline__ void accum8f8w(float* acc, uint2 v, float w) {
    floatx2 f;
    f = __builtin_amdgcn_cvt_pk_f32_fp8((int)v.x, false); acc[0] = fmaf(w, f.x, acc[0]); acc[1] = fmaf(w, f.y, acc[1]);
    f = __builtin_amdgcn_cvt_pk_f32_fp8((int)v.x, true);  acc[2] = fmaf(w, f.x, acc[2]); acc[3] = fmaf(w, f.y, acc[3]);
    f = __builtin_amdgcn_cvt_pk_f32_fp8((int)v.y, false); acc[4] = fmaf(w, f.x, acc[4]); acc[5] = fmaf(w, f.y, acc[5]);
    f = __builtin_amdgcn_cvt_pk_f32_fp8((int)v.y, true);  acc[6] = fmaf(w, f.x, acc[6]); acc[7] = fmaf(w, f.y, acc[7]);
}

__device__ __forceinline__ void agg_node_f8(const uint2* __restrict__ XW2,
                                            const int* __restrict__ rows,
                                            int n, int beg, int end, int quad, int li,
                                            float* acc) {
#pragma unroll
    for (int j = 0; j < 8; ++j) acc[j] = 0.f;
    if (quad == 0) {
        uint2 sv = XW2[(size_t)n * 16 + li];
        accum8f8(acc, sv);
    }
    int e = beg;
    for (; e + 32 <= end; e += 32) {
        int4 ia = *(const int4*)(rows + e + 4 * quad);
        int4 ib = *(const int4*)(rows + e + 16 + 4 * quad);
        uint2 v0 = XW2[(size_t)ia.x * 16 + li];
        uint2 v1 = XW2[(size_t)ia.y * 16 + li];
        uint2 v2 = XW2[(size_t)ia.z * 16 + li];
        uint2 v3 = XW2[(size_t)ia.w * 16 + li];
        uint2 v4 = XW2[(size_t)ib.x * 16 + li];
        uint2 v5 = XW2[(size_t)ib.y * 16 + li];
        uint2 v6 = XW2[(size_t)ib.z * 16 + li];
        uint2 v7 = XW2[(size_t)ib.w * 16 + li];
        accum8f8(acc, v0); accum8f8(acc, v1); accum8f8(acc, v2); accum8f8(acc, v3);
        accum8f8(acc, v4); accum8f8(acc, v5); accum8f8(acc, v6); accum8f8(acc, v7);
    }
    for (; e + 16 <= end; e += 16) {
        int4 ia = *(const int4*)(rows + e + 4 * quad);
        uint2 v0 = XW2[(size_t)ia.x * 16 + li];
        uint2 v1 = XW2[(size_t)ia.y * 16 + li];
        uint2 v2 = XW2[(size_t)ia.z * 16 + li];
        uint2 v3 = XW2[(size_t)ia.w * 16 + li];
        accum8f8(acc, v0); accum8f8(acc, v1); accum8f8(acc, v2); accum8f8(acc, v3);
    }
    if (e < end) {
        int rem = end - e;
        int qb = 4 * quad;
        int4 it = make_int4(0, 0, 0, 0);
        if (qb < rem) it = *(const int4*)(rows + e + qb);
        uint2 v0 = XW2[(size_t)it.x * 16 + li];
        uint2 v1 = XW2[(size_t)it.y * 16 + li];
        uint2 v2 = XW2[(size_t)it.z * 16 + li];
        uint2 v3 = XW2[(size_t)it.w * 16 + li];
        accum8f8w(acc, v0, (qb + 0 < rem) ? 1.f : 0.f);
        accum8f8w(acc, v1, (qb + 1 < rem) ? 1.f : 0.f);
        accum8f8w(acc, v2, (qb + 2 < rem) ? 1.f : 0.f);
        accum8f8w(acc, v3, (qb + 3 < rem) ? 1.f : 0.f);
    }
#pragma unroll
    for (int j = 0; j < 8; ++j) {
        acc[j] += __shfl_xor(acc[j], 16, 64);
        acc[j] += __shfl_xor(acc[j], 32, 64);
    }
}

// conv3: fp8 agg + bias + ReLU + sorted segment-max (no store)
__global__ __launch_bounds__(256) void k_agghmax8(const unsigned char* __restrict__ XWf8,
                                                  const int* __restrict__ begs,
                                                  const int* __restrict__ ends,
                                                  const int* __restrict__ rows,
                                                  const float* __restrict__ dinv,
                                                  const float* __restrict__ b3,
                                                  const int* __restrict__ n2s,
                                                  unsigned int* __restrict__ outmax) {
    int wave = threadIdx.x >> 6, lane = threadIdx.x & 63;
    int quad = lane >> 4, li = lane & 15;
    const uint2* XW2 = (const uint2*)XWf8;
    int wid = blockIdx.x * 4 + wave;
    int n0 = wid * CHUNK;
    int n1 = n0 + CHUNK; if (n1 > NN) n1 = NN;
    float4 bz0 = *(const float4*)(b3 + li * 8);
    float4 bz1 = *(const float4*)(b3 + li * 8 + 4);
    float bias[8] = {bz0.x, bz0.y, bz0.z, bz0.w, bz1.x, bz1.y, bz1.z, bz1.w};
    int cur = -1;
    float runmax[8];
    for (int n = n0; n < n1; ++n) {
        float acc[8];
        agg_node_f8(XW2, rows, n, begs[n], ends[n], quad, li, acc);
        float dn = dinv[n];
        int sg = n2s[n];
        if (sg != cur) {
            if (cur >= 0 && quad == 0) {
#pragma unroll
                for (int j = 0; j < 8; ++j)
                    atomicMax(&outmax[cur * OUTC + 256 + li * 8 + j], __float_as_uint(runmax[j]));
            }
            cur = sg;
#pragma unroll
            for (int j = 0; j < 8; ++j) runmax[j] = fmaxf(acc[j] * dn + bias[j], 0.f);
        } else {
#pragma unroll
            for (int j = 0; j < 8; ++j) runmax[j] = fmaxf(runmax[j], fmaxf(acc[j] * dn + bias[j], 0.f));
        }
    }
    if (cur >= 0 && quad == 0) {
#pragma unroll
        for (int j = 0; j < 8; ++j)
            atomicMax(&outmax[cur * OUTC + 256 + li * 8 + j], __float_as_uint(runmax[j]));
    }
}

// ---------------- launch ----------------
extern "C" void kernel_launch(void* const* d_in, const int* in_sizes, int n_in,
                              void* d_out, int out_size, void* d_ws, size_t ws_size,
                              hipStream_t stream) {
    const float* x   = (const float*)d_in[0];
    const int*   ei  = (const int*)d_in[1];
    const int*   n2s = (const int*)d_in[2];
    const float* W1  = (const float*)d_in[3];
    const float* g1  = (const float*)d_in[5];
    const float* be1 = (const float*)d_in[6];
    const float* W2  = (const float*)d_in[7];
    const float* g2  = (const float*)d_in[9];
    const float* be2 = (const float*)d_in[10];
    const float* W3  = (const float*)d_in[11];
    const float* b3  = (const float*)d_in[12];

    __half* bufA = (__half*)d_ws;                        // NN*128 fp16: raw agg out 'a'
    __half* bufX = bufA + (size_t)NN * 128;              // NN*128 fp16 (or fp8) gather payload
    __half* WT   = bufX + (size_t)NN * 128;              // 3*16384 fp16
    int* rows    = (int*)(WT + 3 * 16384);               // NBUK*CAP
    int* begs    = rows + (size_t)NBUK * CAP;            // NN
    int* ends    = begs + NN;                            // NN
    float* dinv  = (float*)(ends + NN);                  // NN
    int* gcur    = (int*)(dinv + NN);                    // NBUK
    float* sums  = (float*)(gcur + NBUK);                // 2 * NBANK * 256

    const int* erow = ei;
    const int* ecol = ei + NE;
    unsigned int* outmax = (unsigned int*)d_out;

    k_init<<<512, 256, 0, stream>>>(W1, W2, W3, WT, outmax, gcur, sums);
    k_fused1<<<B_BUCKET + B_GEMM, 256, 0, stream>>>(erow, ecol, gcur, rows, x, WT, bufX);
    k_csrB<<<NBUK, 256, 0, stream>>>(rows, gcur, begs, ends, dinv, bufX);

    // conv1: gather fp16 -> raw a1 + stats
    k_agghs<<<AGG_BLOCKS, 256, 0, stream>>>(bufX, begs, ends, rows, dinv, bufA, sums);
    // fused: h1 = relu(BN(a1)) on the fly -> gemm @W2 (fp16 out, prescaled)  ||  segmax(h1)
    k_fused2<0><<<B_GEMM + B_MAX, 256, 0, stream>>>(bufA, sums, g1, be1, WT + 16384, dinv,
                                                    n2s, outmax, 0, (void*)bufX);

    // conv2
    k_agghs<<<AGG_BLOCKS, 256, 0, stream>>>(bufX, begs, ends, rows, dinv, bufA, sums + NBANK * 256);
    // fused: h2 -> gemm @W3 (fp8 out, prescaled)  ||  segmax(h2)
    k_fused2<1><<<B_GEMM + B_MAX, 256, 0, stream>>>(bufA, sums + NBANK * 256, g2, be2, WT + 32768,
                                                    dinv, n2s, outmax, 128, (void*)bufX);

    // conv3: fp8 gather + bias + relu + segmax
    k_agghmax8<<<AGG_BLOCKS, 256, 0, stream>>>((const unsigned char*)bufX, begs, ends, rows,
                                               dinv, b3, n2s, outmax);
}